// Round 9
// baseline (284.390 us; speedup 1.0000x reference)
//
#include <hip/hip_runtime.h>
#include <math.h>

#define NB 8
#define NN 2048
#define IN_DIM 256
#define OUT_DIM 64
#define ALPHA 0.2f
#define WH_BLOCKS 256
#define PACK_BLOCKS 4096

typedef __attribute__((ext_vector_type(8))) short bf16x8;
typedef __attribute__((ext_vector_type(4))) float f32x4;
typedef __attribute__((ext_vector_type(4))) int   i32x4;

// float -> bf16 (RNE), bit trick (no NaN inputs here)
__device__ __forceinline__ unsigned short f2bf(float x) {
    union { float f; unsigned u; } v; v.f = x;
    unsigned r = v.u + 0x7FFF + ((v.u >> 16) & 1);
    return (unsigned short)(r >> 16);
}

// ---------------------------------------------------------------------------
// Kernel 1 (fused "prep"):
//  blocks [0,256):            Wh = h@W via MFMA -> Whbt [b][d][j] bf16, s1, s2
//  blocks [256,256+4096):     adj -> 1-bit mask, COALESCED: lane reads
//                             adj[u*64+lane] (256 B/wave), __ballot -> 1 ull.
//                             bit l of bits64[u] == (adj[64u+l] != 0).
// ---------------------------------------------------------------------------
#define WT_STRIDE 264
__global__ __launch_bounds__(256) void prep_kernel(const float* __restrict__ h,
                                                   const float* __restrict__ W,
                                                   const float* __restrict__ a,
                                                   const int* __restrict__ adj,
                                                   unsigned long long* __restrict__ bits64,
                                                   unsigned short* __restrict__ Whbt,
                                                   float* __restrict__ s1,
                                                   float* __restrict__ s2) {
    __shared__ unsigned short Wt[OUT_DIM * WT_STRIDE];
    const int t = threadIdx.x;
    const int bid = blockIdx.x;

    if (bid >= WH_BLOCKS) {
        // ---------------- pack role ----------------
        const int lane = t & 63;
        const int wg = (bid - WH_BLOCKS) * 4 + (t >> 6);   // wave 0..16383
        const long base = (long)wg * 32;                   // ull index base
        const int* ap = adj + base * 64 + lane;
        #pragma unroll 4
        for (int it = 0; it < 32; ++it) {
            const int v = __builtin_nontemporal_load(ap + it * 64);
            const unsigned long long mk = __ballot(v != 0);
            if (lane == 0) bits64[base + it] = mk;
        }
        return;
    }

    // ---------------- wh role (unchanged structure) ----------------
    #pragma unroll 8
    for (int rep = 0; rep < 64; ++rep) {
        const int id = rep * 256 + t;
        const int k = id >> 6, n = id & 63;
        Wt[n * WT_STRIDE + k] = f2bf(W[id]);
    }
    __syncthreads();

    const int lane = t & 63, wv = t >> 6;
    const int m = lane & 15, quad = lane >> 4;
    const long gr0 = (long)(bid * 4 + wv) * 16;

    f32x4 acc[4];
    #pragma unroll
    for (int nt = 0; nt < 4; ++nt) acc[nt] = (f32x4){0.f, 0.f, 0.f, 0.f};

    #pragma unroll
    for (int ks = 0; ks < 8; ++ks) {
        const int k0 = ks * 32;
        const float* hp = h + (gr0 + m) * IN_DIM + k0 + quad * 8;
        const float4 ha = *(const float4*)hp;
        const float4 hb = *(const float4*)(hp + 4);
        bf16x8 af;
        af[0] = (short)f2bf(ha.x); af[1] = (short)f2bf(ha.y);
        af[2] = (short)f2bf(ha.z); af[3] = (short)f2bf(ha.w);
        af[4] = (short)f2bf(hb.x); af[5] = (short)f2bf(hb.y);
        af[6] = (short)f2bf(hb.z); af[7] = (short)f2bf(hb.w);
        #pragma unroll
        for (int nt = 0; nt < 4; ++nt) {
            const bf16x8 bf_ = *(const bf16x8*)(const void*)
                &Wt[(nt * 16 + m) * WT_STRIDE + k0 + quad * 8];
            acc[nt] = __builtin_amdgcn_mfma_f32_16x16x32_bf16(af, bf_, acc[nt], 0, 0, 0);
        }
    }

    const int b  = (int)(gr0 >> 11);
    const int ib = (int)(gr0 & 2047);

    #pragma unroll
    for (int nt = 0; nt < 4; ++nt) {
        ushort4 w4;
        w4.x = f2bf(acc[nt][0]); w4.y = f2bf(acc[nt][1]);
        w4.z = f2bf(acc[nt][2]); w4.w = f2bf(acc[nt][3]);
        *(ushort4*)&Whbt[((long)(b * OUT_DIM + nt * 16 + m) << 11) + ib + quad * 4] = w4;
    }

    float a1v[4], a2v[4];
    #pragma unroll
    for (int nt = 0; nt < 4; ++nt) {
        a1v[nt] = a[nt * 16 + m];
        a2v[nt] = a[OUT_DIM + nt * 16 + m];
    }
    #pragma unroll
    for (int reg = 0; reg < 4; ++reg) {
        float p1 = 0.f, p2 = 0.f;
        #pragma unroll
        for (int nt = 0; nt < 4; ++nt) {
            p1 += acc[nt][reg] * a1v[nt];
            p2 += acc[nt][reg] * a2v[nt];
        }
        #pragma unroll
        for (int off = 1; off < 16; off <<= 1) {
            p1 += __shfl_xor(p1, off, 64);
            p2 += __shfl_xor(p2, off, 64);
        }
        if (m == 0) {
            s1[gr0 + quad * 4 + reg] = p1;
            s2[gr0 + quad * 4 + reg] = p2;
        }
    }
}

// ---------------------------------------------------------------------------
// Kernel 2: masked softmax + P@Wh via bf16 MFMA, writing OUT directly.
// Block = 16 i-rows; wave wv owns j-slice [wv*512, wv*512+512), 16 steps of
// 32 j, unroll 2 (VGPR-bounded).  Mask bits + Whbt + s2 are L2-resident.
// Denominators via 5th MFMA with B=1.0.  Epilogue: 4 wave-partials combined
// in LDS (pad 65: <=2-way banks), divide, coalesced store.  One barrier.
// Grid NB*(NN/16) = 1024 blocks.
// ---------------------------------------------------------------------------
__device__ __forceinline__ float pcalc(unsigned mask, int bit, float s2e, float s1v) {
    float e = s1v + s2e;
    e = e > 0.f ? e : ALPHA * e;
    const float p = __expf(e);
    return ((mask >> bit) & 1u) ? p : 0.f;
}

__global__ __launch_bounds__(256, 4) void attn_kernel(const unsigned long long* __restrict__ bits64,
                                                      const unsigned short* __restrict__ Whbt,
                                                      const float* __restrict__ s1,
                                                      const float* __restrict__ s2,
                                                      float* __restrict__ out) {
    __shared__ float ored[4][16][65];
    __shared__ float olsum[4][16];

    const int t = threadIdx.x, lane = t & 63, wv = t >> 6;
    const int bid = blockIdx.x;
    const int b   = bid >> 7;
    const int i0  = (bid & 127) * 16;
    const int jlo = wv * (NN / 4);             // 512-wide slice, 16 steps

    const int m = lane & 15, quad = lane >> 4;

    // mask preload: row i0+m, slice wv -> 8 ulls = 4 x i32x4
    const i32x4* mp = (const i32x4*)bits64 + ((long)(b * NN + i0 + m) << 4) + (wv << 2);
    i32x4 mku[4];
    #pragma unroll
    for (int g = 0; g < 4; ++g) mku[g] = mp[g];

    const float* s2p = s2 + b * NN + jlo + quad * 8;
    const unsigned short* wbase = Whbt + ((long)(b * OUT_DIM) << 11) + jlo + quad * 8;
    const float s1v = s1[b * NN + i0 + m];

    f32x4 acc[4];
    #pragma unroll
    for (int nt = 0; nt < 4; ++nt) acc[nt] = (f32x4){0.f, 0.f, 0.f, 0.f};
    f32x4 racc = (f32x4){0.f, 0.f, 0.f, 0.f};

    bf16x8 bones;
    #pragma unroll
    for (int e = 0; e < 8; ++e) bones[e] = (short)0x3F80;   // 1.0 bf16

    float4 sv0 = *(const float4*)s2p;
    float4 sv1 = *(const float4*)(s2p + 4);

    #pragma unroll 2
    for (int ks = 0; ks < 16; ++ks) {
        const int j0 = ks * 32;
        const unsigned mask = (unsigned)mku[ks >> 2][ks & 3];

        bf16x8 bfr[4];
        #pragma unroll
        for (int nt = 0; nt < 4; ++nt)
            bfr[nt] = *(const bf16x8*)(const void*)
                &wbase[(((long)(nt * 16 + m)) << 11) + j0];

        const float4 cs0 = sv0, cs1 = sv1;
        if (ks < 15) {
            sv0 = *(const float4*)(s2p + j0 + 32);
            sv1 = *(const float4*)(s2p + j0 + 36);
        }

        const int bb = quad * 8;
        float pv[8];
        pv[0] = pcalc(mask, bb + 0, cs0.x, s1v);
        pv[1] = pcalc(mask, bb + 1, cs0.y, s1v);
        pv[2] = pcalc(mask, bb + 2, cs0.z, s1v);
        pv[3] = pcalc(mask, bb + 3, cs0.w, s1v);
        pv[4] = pcalc(mask, bb + 4, cs1.x, s1v);
        pv[5] = pcalc(mask, bb + 5, cs1.y, s1v);
        pv[6] = pcalc(mask, bb + 6, cs1.z, s1v);
        pv[7] = pcalc(mask, bb + 7, cs1.w, s1v);

        bf16x8 af;
        #pragma unroll
        for (int e = 0; e < 8; ++e) af[e] = (short)f2bf(pv[e]);

        #pragma unroll
        for (int nt = 0; nt < 4; ++nt)
            acc[nt] = __builtin_amdgcn_mfma_f32_16x16x32_bf16(af, bfr[nt], acc[nt], 0, 0, 0);
        racc = __builtin_amdgcn_mfma_f32_16x16x32_bf16(af, bones, racc, 0, 0, 0);
    }

    // ---- combine 4 wave-partials in LDS, normalize, store ----
    #pragma unroll
    for (int nt = 0; nt < 4; ++nt)
        #pragma unroll
        for (int reg = 0; reg < 4; ++reg)
            ored[wv][quad * 4 + reg][nt * 16 + m] = acc[nt][reg];
    if (m == 0) {
        #pragma unroll
        for (int reg = 0; reg < 4; ++reg)
            olsum[wv][quad * 4 + reg] = racc[reg];   // rowsum, same for all m
    }
    __syncthreads();

    const int col = t & 63;
    const int rb  = t >> 6;
    float* ob = out + ((long)(b * NN + i0) << 6);
    #pragma unroll
    for (int k2 = 0; k2 < 4; ++k2) {
        const int row = rb + 4 * k2;
        const float l = olsum[0][row] + olsum[1][row] + olsum[2][row] + olsum[3][row];
        const float v = ored[0][row][col] + ored[1][row][col]
                      + ored[2][row][col] + ored[3][row][col];
        ob[(long)row * OUT_DIM + col] = v / l;
    }
}

// ---------------------------------------------------------------------------
extern "C" void kernel_launch(void* const* d_in, const int* in_sizes, int n_in,
                              void* d_out, int out_size, void* d_ws, size_t ws_size,
                              hipStream_t stream) {
    const float* h   = (const float*)d_in[0];
    const int*   adj = (const int*)d_in[1];
    const float* W   = (const float*)d_in[2];
    const float* a   = (const float*)d_in[3];
    float* out = (float*)d_out;

    unsigned long long* bits64 = (unsigned long long*)d_ws;            // 4 MB
    unsigned short* Whbt = (unsigned short*)(bits64 + NB * NN * NN / 64); // 2 MB
    float* s1 = (float*)(Whbt + (long)NB * NN * OUT_DIM);              // 16K f32
    float* s2 = s1 + NB * NN;                                          // 16K f32

    prep_kernel<<<WH_BLOCKS + PACK_BLOCKS, 256, 0, stream>>>(h, W, a, adj, bits64,
                                                             Whbt, s1, s2);
    attn_kernel<<<NB * (NN / 16), 256, 0, stream>>>(bits64, Whbt, s1, s2, out);
}